// Round 9
// baseline (101.291 us; speedup 1.0000x reference)
//
#include <hip/hip_runtime.h>
#include <stdint.h>

// PoissonNeuronTransform — bit-exact vs the harness's NUMPY reference (ref=np).
// Validated (absmax 0.0, R11-R18): threefry2x32 partitionable bits, uniform
// bit-trick, fdlibm log1pf port (dead c-branch removed, proof R17), +0.002f,
// sequential f32 cumsum, early exit (monotone RN-fadd), wave-internal ballot
// lane-refill, LPT (descending-rate) handout.
// R19: hoisted per-element f64 reciprocal into setup (LDS).
// R21/22: kEPW=256 (1024 blocks) straggler amortization. 62.5->59.3us.
// R23: 2-eval unroll (per-lane ILP). 59.3->57.4us.
// R24: Markstein CR division by rate (f64 out of the loop). 57.4->58.7.
// R25: Markstein division inside log1pf (vcc-free). 58.7->53.4us.
// R26: 6 waves/SIMD — REVERTED (53.4->54.7). Scheduling axis exhausted;
//   only instruction cuts move wall time (law held R25/R26/R27).
// R27: revert sched + rare-path tiny-select ballot guard. 54.7->52.5us.
// R28 (perf only, THIS ROUND): packed-f32 (VOP3P) dual-eval pipeline.
//   The two ILP eval-chains are identical op sequences on different data.
//   gfx950 has v_pk_fma/add/mul_f32 (per-half IEEE-identical). Pack ALL
//   float math (uniform construct, log1pf add/mul/poly, both Markstein
//   chains, +0.002) into f32x2; threefry/int-decompose/selects stay scalar
//   per half; v_rcp_f32 has no pk form (2x scalar). Exact identity
//   x = 1.0-v replaces uu=v-1; x=-uu (Sterbenz, same bits). Poly remains
//   mul+add (contract off); only explicit fmaf becomes pk_fma. ~-30
//   inst/round of ~274. Per-half IEEE ops -> bit-exact by construction.

static constexpr int      kSpikes = 100;              // NUM_SPIKES
static constexpr int      kBlocks = 1024;             // x256 thr = 4096 waves
static constexpr uint32_t kEPW    = 256;              // elements per wave

typedef float f32x2 __attribute__((ext_vector_type(2)));

__device__ __forceinline__ f32x2 pk_fma(f32x2 a, f32x2 b, f32x2 c) {
#if __has_builtin(__builtin_elementwise_fma)
  return __builtin_elementwise_fma(a, b, c);
#else
  f32x2 d;
  asm("v_pk_fma_f32 %0, %1, %2, %3" : "=v"(d) : "v"(a), "v"(b), "v"(c));
  return d;
#endif
}

__device__ __forceinline__ uint32_t rotl32(uint32_t v, uint32_t d) {
  return (v << d) | (v >> (32u - d));
}

// threefry2x32 with key (0, 42) — matches jax.random.key(42).
__device__ __forceinline__ void threefry2x32_0_42(uint32_t x0, uint32_t x1,
                                                  uint32_t& o0, uint32_t& o1) {
  const uint32_t ks0 = 0u;
  const uint32_t ks1 = 42u;
  const uint32_t ks2 = 0x1BD11BDAu ^ 0u ^ 42u;
  uint32_t a = x0 + ks0;
  uint32_t b = x1 + ks1;
#define TF_ROUND(r) { a += b; b = rotl32(b, (r)); b ^= a; }
  TF_ROUND(13u) TF_ROUND(15u) TF_ROUND(26u) TF_ROUND(6u)
  a += ks1; b += ks2 + 1u;
  TF_ROUND(17u) TF_ROUND(29u) TF_ROUND(16u) TF_ROUND(24u)
  a += ks2; b += ks0 + 2u;
  TF_ROUND(13u) TF_ROUND(15u) TF_ROUND(26u) TF_ROUND(6u)
  a += ks0; b += ks1 + 3u;
  TF_ROUND(17u) TF_ROUND(29u) TF_ROUND(16u) TF_ROUND(24u)
  a += ks1; b += ks2 + 4u;
  TF_ROUND(13u) TF_ROUND(15u) TF_ROUND(26u) TF_ROUND(6u)
  a += ks2; b += ks0 + 5u;
#undef TF_ROUND
  o0 = a; o1 = b;
}

// Packed branchless fdlibm s_log1pf for x = -m*2^-23, m in [0, 2^23) —
// bit-exact per half (R12 port; c-branch removed, proof R17; R25 vcc-free
// Markstein division; R27 rare tiny-path ballot guard; R28 f32x2 packing:
// float adds/muls/fmas are per-half IEEE-identical pk ops, int decompose
// and selects stay scalar per half).
__device__ __forceinline__ f32x2 fdlibm_log1pf_pk(f32x2 x) {
#pragma clang fp contract(off)
  const float ln2_hi = __uint_as_float(0x3f317180u);
  const float ln2_lo = __uint_as_float(0x3717f7d1u);
  const float Lp1 = __uint_as_float(0x3F2AAAABu);
  const float Lp2 = __uint_as_float(0x3ECCCCCDu);
  const float Lp3 = __uint_as_float(0x3E924925u);
  const float Lp4 = __uint_as_float(0x3E638E29u);
  const float Lp5 = __uint_as_float(0x3E3A3325u);
  const float Lp6 = __uint_as_float(0x3E1CD04Fu);
  const float Lp7 = __uint_as_float(0x3E178897u);

  uint32_t hx0 = __float_as_uint(x.x);
  uint32_t hx1 = __float_as_uint(x.y);
  uint32_t ax0 = hx0 & 0x7fffffffu;
  uint32_t ax1 = hx1 & 0x7fffffffu;

  f32x2 u = x + 1.0f;                       // pk add
  uint32_t hu0 = __float_as_uint(u.x);
  uint32_t hu1 = __float_as_uint(u.y);
  int k0 = (int)(hu0 >> 23) - 127;
  int k1 = (int)(hu1 >> 23) - 127;
  uint32_t m0 = hu0 & 0x007fffffu;
  uint32_t m1 = hu1 & 0x007fffffu;
  bool h0 = (m0 >= 0x3504f7u);
  bool h1 = (m1 >= 0x3504f7u);
  int k20 = h0 ? (k0 + 1) : k0;
  int k21 = h1 ? (k1 + 1) : k1;
  f32x2 u2v = { __uint_as_float(m0 | (h0 ? 0x3f000000u : 0x3f800000u)),
                __uint_as_float(m1 | (h1 ? 0x3f000000u : 0x3f800000u)) };
  f32x2 f2v = u2v - 1.0f;                   // pk add

  bool c00 = ((int32_t)hx0 <= (int32_t)0xbe95f61fu);
  bool c01 = ((int32_t)hx1 <= (int32_t)0xbe95f61fu);
  f32x2 kf = { c00 ? 0.0f : (float)k20, c01 ? 0.0f : (float)k21 };
  f32x2 ff = { c00 ? x.x : f2v.x, c01 ? x.y : f2v.y };

  f32x2 hfsq = (0.5f * ff) * ff;            // 2 pk mul
  // Markstein division s = RN(ff / (2+ff)), vcc-free (R25), packed:
  f32x2 den = 2.0f + ff;                    // pk add
  f32x2 y0 = { __builtin_amdgcn_rcpf(den.x),
               __builtin_amdgcn_rcpf(den.y) };   // v_rcp_f32 x2, <=1 ulp
  const f32x2 kOne = {1.0f, 1.0f};
  f32x2 e  = pk_fma(-den, y0, kOne);        // exact-fma residual
  f32x2 y1 = pk_fma(y0, e, y0);             // reciprocal err ~2^-25
  f32x2 q0 = ff * y1;
  f32x2 r1 = pk_fma(-den, q0, ff);          // exact residual
  f32x2 s  = pk_fma(r1, y1, q0);            // == RN(ff/den), Markstein
  f32x2 z = s * s;
  // Poly stays separate mul+add (contract off) — bit-exact vs scalar:
  f32x2 R = z * (Lp1 + z * (Lp2 + z * (Lp3 + z * (Lp4 +
            z * (Lp5 + z * (Lp6 + z * Lp7))))));
  f32x2 lowsum = s * (hfsq + R) + kf * ln2_lo;
  f32x2 res = kf * ln2_hi - ((hfsq - lowsum) - ff);

  // R27: tiny path (|x| < 2^-15, P = 2^-15/eval) behind wave-uniform rare
  // branch; selects identical to the original, scalar per half.
  if (__builtin_expect(
        __ballot((ax0 < 0x38000000u) || (ax1 < 0x38000000u)) != 0ull, 0)) {
    float t0 = x.x - (x.x * x.x) * 0.5f;
    float t1 = x.y - (x.y * x.y) * 0.5f;
    float r0 = (ax0 < 0x38000000u) ? ((ax0 < 0x33800000u) ? x.x : t0) : res.x;
    float r1s = (ax1 < 0x38000000u) ? ((ax1 < 0x33800000u) ? x.y : t1) : res.y;
    res.x = r0;
    res.y = r1s;
  }
  return res;
}

// Both spike-interval deltas for counters {jc, jc+2^20}: bits -> uniform ->
// exponential -> / rate via packed Markstein CR division -> + 0.002.
// x = 1.0 - v is Sterbenz-exact == -(v - 1.0) == -uu (identical bits).
__device__ __forceinline__ f32x2 spike_delta_pair(uint32_t jc,
                                                  float rt, float ry) {
#pragma clang fp contract(off)
  uint32_t p0, p1, q0i, q1i;
  threefry2x32_0_42(0u, jc, p0, p1);
  threefry2x32_0_42(0u, jc + 0x100000u, q0i, q1i);
  uint32_t bits0 = p0 ^ p1;
  uint32_t bits1 = q0i ^ q1i;
  f32x2 v = { __uint_as_float((bits0 >> 9) | 0x3f800000u),
              __uint_as_float((bits1 >> 9) | 0x3f800000u) };
  f32x2 x = 1.0f - v;                       // == -uu, exact
  f32x2 expo = -fdlibm_log1pf_pk(x);        // exact negation
  f32x2 ry2 = {ry, ry};
  f32x2 nrt = {-rt, -rt};
  f32x2 q0 = expo * ry2;                    // pk mul
  f32x2 rr = pk_fma(nrt, q0, expo);         // exact residual (fma)
  f32x2 qq = pk_fma(rr, ry2, q0);           // == RN(expo/rt)
  return qq + 0.002f;                       // pk add
}

__global__ void __launch_bounds__(256) poisson_count_kernel(
    const float* __restrict__ rates, int* __restrict__ out) {
#pragma clang fp contract(off)
  __shared__ uint32_t pool_idx[4][kEPW];   // local element index (LPT order)
  __shared__ float2   pool_ry[4][kEPW];    // {rate, RN(1/rate)} per element
  int wslot = (int)threadIdx.x >> 6;
  int lane  = (int)threadIdx.x & 63;
  int wid   = blockIdx.x * 4 + wslot;
  uint32_t base = (uint32_t)wid * kEPW;
  uint64_t lmask_lt = (1ull << lane) - 1ull;

  // ---- one-time setup: LPT buckets + hoisted CR f32 reciprocals ----
  {
    float r[4];
    int   bb[4];
    uint32_t pos[4];
#pragma unroll
    for (int i = 0; i < 4; ++i) {
      r[i] = rates[base + (uint32_t)(i * 64) + (uint32_t)lane];
      int q = (int)(r[i] * 0.4f);
      q = q > 7 ? 7 : q;
      bb[i] = 7 - q;                       // bucket 0 = highest rates
    }
    uint32_t off = 0;
#pragma unroll
    for (int b = 0; b < 8; ++b) {
      uint64_t m0 = __ballot(bb[0] == b);
      uint64_t m1 = __ballot(bb[1] == b);
      uint64_t m2 = __ballot(bb[2] == b);
      uint64_t m3 = __ballot(bb[3] == b);
      uint32_t c0 = (uint32_t)__popcll(m0);
      uint32_t c1 = (uint32_t)__popcll(m1);
      uint32_t c2 = (uint32_t)__popcll(m2);
      uint32_t c3 = (uint32_t)__popcll(m3);
      if (bb[0] == b) pos[0] = off + (uint32_t)__popcll(m0 & lmask_lt);
      if (bb[1] == b) pos[1] = off + c0 + (uint32_t)__popcll(m1 & lmask_lt);
      if (bb[2] == b) pos[2] = off + c0 + c1 + (uint32_t)__popcll(m2 & lmask_lt);
      if (bb[3] == b) pos[3] = off + c0 + c1 + c2 + (uint32_t)__popcll(m3 & lmask_lt);
      off += c0 + c1 + c2 + c3;
    }
#pragma unroll
    for (int i = 0; i < 4; ++i) {
      pool_idx[wslot][pos[i]] = (uint32_t)(i * 64) + (uint32_t)lane;
      // CR f32 reciprocal via f64 (setup-only f64; none in the main loop)
      pool_ry[wslot][pos[i]] = make_float2(r[i], (float)(1.0 / (double)r[i]));
    }
  }
  __syncthreads();

  // ---- main loop: ballot lane-refill; TWO sequential evals per round ----
  uint32_t next = 0;                       // wave-uniform: elements handed out
  uint32_t o = 0;
  uint32_t jc = 0;                         // threefry counter = (s<<20) + o
  float run = 0.0f;
  int s = 0;                               // evals consumed (always even)
  float rt = 1.0f, ry = 1.0f;              // rate, RN(1/rate)
  bool active = false;

  while (true) {
    uint64_t needmask = __ballot(!active);
    if (needmask != 0ull) {
      uint32_t avail = kEPW - next;
      if (avail != 0u) {
        if (!active) {
          uint32_t rank = (uint32_t)__popcll(needmask & lmask_lt);
          if (rank < avail) {
            uint32_t slot = next + rank;
            o = base + pool_idx[wslot][slot];
            float2 ryv = pool_ry[wslot][slot];
            rt = ryv.x; ry = ryv.y;
            run = 0.0f; s = 0; jc = o;     // s=0 -> jc = o
            active = true;
          }
        }
        uint32_t nneed = (uint32_t)__popcll(needmask);
        next += (nneed < avail) ? nneed : avail;
      } else if (needmask == ~0ull) {
        break;                             // pool empty, all lanes idle
      }
    }

    if (active) {
      // Packed dual-eval pipeline; sequential RN cumsum.
      f32x2 d = spike_delta_pair(jc, rt, ry);   // evals s, s+1
      float run1 = run + d.x;
      float run2 = run1 + d.y;
      s += 2;
      bool lt1 = (run1 < 1.0f);
      bool lt2 = (run2 < 1.0f);
      // monotone: d.y > 0 => (lt2 => lt1); single exit branch.
      if (!lt2 || s == kSpikes) {
        // count: crossed in this pair -> lt1 ? s-1 : s-2; else cap -> 100.
        out[o] = lt2 ? kSpikes : (lt1 ? (s - 1) : (s - 2));
        active = false;
      } else {
        run = run2;
        jc += 0x200000u;                   // += 2*2^20
      }
    }
  }
}

extern "C" void kernel_launch(void* const* d_in, const int* in_sizes, int n_in,
                              void* d_out, int out_size, void* d_ws, size_t ws_size,
                              hipStream_t stream) {
  const float* rates = (const float*)d_in[0];
  int* out = (int*)d_out;
  (void)in_sizes; (void)n_in; (void)out_size; (void)d_ws; (void)ws_size;
  poisson_count_kernel<<<kBlocks, 256, 0, stream>>>(rates, out);
}

// Round 10
// 101.153 us; speedup vs baseline: 1.0014x; 1.0014x over previous
//
#include <hip/hip_runtime.h>
#include <stdint.h>

// PoissonNeuronTransform — bit-exact vs the harness's NUMPY reference (ref=np).
// Validated (absmax 0.0, R11-R18): threefry2x32 partitionable bits, uniform
// bit-trick, fdlibm log1pf port (dead c-branch removed, proof R17), +0.002f,
// sequential f32 cumsum, early exit (monotone RN-fadd), wave-internal ballot
// lane-refill, LPT (descending-rate) handout.
// R19: hoisted per-element f64 reciprocal into setup (LDS).
// R21/22: kEPW=256 (1024 blocks) straggler amortization. 62.5->59.3us.
// R23: 2-eval unroll (per-lane ILP). 59.3->57.4us.
// R24: Markstein CR division by rate (f64 out of the loop). 57.4->58.7.
// R25: Markstein division inside log1pf (vcc-free). 58.7->53.4us.
// R26: 6 waves/SIMD — REVERTED (53.4->54.7). Scheduling axis exhausted.
// R27: rare-path tiny-select ballot guard. 54.7->52.5us.
// R28: packed-f32 (VOP3P) dual-eval pipeline. 52.5->54.2 BUT VALUBusy
//   81->70: pk ops CUT busy-cycles 11% yet welded the two eval-chains into
//   one serial chain (ILP-2 -> ILP-1); stalls grew more than inst shrank.
// R29 (perf only, THIS ROUND): 4 evals/round = TWO independent packed
//   chains. Keeps R28's pk instruction diet AND restores chain-level ILP-2.
//   Accounting: ~109 inst/eval-slot (437/4) vs R27's 137, waste +1 eval/elem
//   (4-granularity) -> net -13% per-element inst. Pool balance: ideal ~12.3
//   rounds > straggler ~9 (LPT). 100 % 4 == 0 so the cap lands exactly.
//   Exit count branchless via monotone lt flags: crossed -> (s-4)+lt1+lt2+
//   lt3; cap -> 100. Same per-eval bits in the same cumsum order ->
//   bit-exact by construction.

static constexpr int      kSpikes = 100;              // NUM_SPIKES
static constexpr int      kBlocks = 1024;             // x256 thr = 4096 waves
static constexpr uint32_t kEPW    = 256;              // elements per wave

typedef float f32x2 __attribute__((ext_vector_type(2)));

__device__ __forceinline__ f32x2 pk_fma(f32x2 a, f32x2 b, f32x2 c) {
#if __has_builtin(__builtin_elementwise_fma)
  return __builtin_elementwise_fma(a, b, c);
#else
  f32x2 d;
  asm("v_pk_fma_f32 %0, %1, %2, %3" : "=v"(d) : "v"(a), "v"(b), "v"(c));
  return d;
#endif
}

__device__ __forceinline__ uint32_t rotl32(uint32_t v, uint32_t d) {
  return (v << d) | (v >> (32u - d));
}

// threefry2x32 with key (0, 42) — matches jax.random.key(42).
__device__ __forceinline__ void threefry2x32_0_42(uint32_t x0, uint32_t x1,
                                                  uint32_t& o0, uint32_t& o1) {
  const uint32_t ks0 = 0u;
  const uint32_t ks1 = 42u;
  const uint32_t ks2 = 0x1BD11BDAu ^ 0u ^ 42u;
  uint32_t a = x0 + ks0;
  uint32_t b = x1 + ks1;
#define TF_ROUND(r) { a += b; b = rotl32(b, (r)); b ^= a; }
  TF_ROUND(13u) TF_ROUND(15u) TF_ROUND(26u) TF_ROUND(6u)
  a += ks1; b += ks2 + 1u;
  TF_ROUND(17u) TF_ROUND(29u) TF_ROUND(16u) TF_ROUND(24u)
  a += ks2; b += ks0 + 2u;
  TF_ROUND(13u) TF_ROUND(15u) TF_ROUND(26u) TF_ROUND(6u)
  a += ks0; b += ks1 + 3u;
  TF_ROUND(17u) TF_ROUND(29u) TF_ROUND(16u) TF_ROUND(24u)
  a += ks1; b += ks2 + 4u;
  TF_ROUND(13u) TF_ROUND(15u) TF_ROUND(26u) TF_ROUND(6u)
  a += ks2; b += ks0 + 5u;
#undef TF_ROUND
  o0 = a; o1 = b;
}

// Packed branchless fdlibm s_log1pf for x = -m*2^-23, m in [0, 2^23) —
// bit-exact per half (R12 port; c-branch removed, proof R17; R25 vcc-free
// Markstein division; R27 rare tiny-path ballot guard; R28 f32x2 packing).
__device__ __forceinline__ f32x2 fdlibm_log1pf_pk(f32x2 x) {
#pragma clang fp contract(off)
  const float ln2_hi = __uint_as_float(0x3f317180u);
  const float ln2_lo = __uint_as_float(0x3717f7d1u);
  const float Lp1 = __uint_as_float(0x3F2AAAABu);
  const float Lp2 = __uint_as_float(0x3ECCCCCDu);
  const float Lp3 = __uint_as_float(0x3E924925u);
  const float Lp4 = __uint_as_float(0x3E638E29u);
  const float Lp5 = __uint_as_float(0x3E3A3325u);
  const float Lp6 = __uint_as_float(0x3E1CD04Fu);
  const float Lp7 = __uint_as_float(0x3E178897u);

  uint32_t hx0 = __float_as_uint(x.x);
  uint32_t hx1 = __float_as_uint(x.y);
  uint32_t ax0 = hx0 & 0x7fffffffu;
  uint32_t ax1 = hx1 & 0x7fffffffu;

  f32x2 u = x + 1.0f;                       // pk add
  uint32_t hu0 = __float_as_uint(u.x);
  uint32_t hu1 = __float_as_uint(u.y);
  int k0 = (int)(hu0 >> 23) - 127;
  int k1 = (int)(hu1 >> 23) - 127;
  uint32_t m0 = hu0 & 0x007fffffu;
  uint32_t m1 = hu1 & 0x007fffffu;
  bool h0 = (m0 >= 0x3504f7u);
  bool h1 = (m1 >= 0x3504f7u);
  int k20 = h0 ? (k0 + 1) : k0;
  int k21 = h1 ? (k1 + 1) : k1;
  f32x2 u2v = { __uint_as_float(m0 | (h0 ? 0x3f000000u : 0x3f800000u)),
                __uint_as_float(m1 | (h1 ? 0x3f000000u : 0x3f800000u)) };
  f32x2 f2v = u2v - 1.0f;                   // pk add

  bool c00 = ((int32_t)hx0 <= (int32_t)0xbe95f61fu);
  bool c01 = ((int32_t)hx1 <= (int32_t)0xbe95f61fu);
  f32x2 kf = { c00 ? 0.0f : (float)k20, c01 ? 0.0f : (float)k21 };
  f32x2 ff = { c00 ? x.x : f2v.x, c01 ? x.y : f2v.y };

  f32x2 hfsq = (0.5f * ff) * ff;            // pk muls
  // Markstein division s = RN(ff / (2+ff)), vcc-free (R25), packed:
  f32x2 den = 2.0f + ff;                    // pk add
  f32x2 y0 = { __builtin_amdgcn_rcpf(den.x),
               __builtin_amdgcn_rcpf(den.y) };   // v_rcp_f32 x2, <=1 ulp
  const f32x2 kOne = {1.0f, 1.0f};
  f32x2 e  = pk_fma(-den, y0, kOne);        // exact-fma residual
  f32x2 y1 = pk_fma(y0, e, y0);             // reciprocal err ~2^-25
  f32x2 q0 = ff * y1;
  f32x2 r1 = pk_fma(-den, q0, ff);          // exact residual
  f32x2 s  = pk_fma(r1, y1, q0);            // == RN(ff/den), Markstein
  f32x2 z = s * s;
  // Poly stays separate mul+add (contract off) — bit-exact vs scalar:
  f32x2 R = z * (Lp1 + z * (Lp2 + z * (Lp3 + z * (Lp4 +
            z * (Lp5 + z * (Lp6 + z * Lp7))))));
  f32x2 lowsum = s * (hfsq + R) + kf * ln2_lo;
  f32x2 res = kf * ln2_hi - ((hfsq - lowsum) - ff);

  // R27: tiny path (|x| < 2^-15, P = 2^-15/eval) behind wave-uniform rare
  // branch; selects identical to the original, scalar per half.
  if (__builtin_expect(
        __ballot((ax0 < 0x38000000u) || (ax1 < 0x38000000u)) != 0ull, 0)) {
    float t0 = x.x - (x.x * x.x) * 0.5f;
    float t1 = x.y - (x.y * x.y) * 0.5f;
    float r0 = (ax0 < 0x38000000u) ? ((ax0 < 0x33800000u) ? x.x : t0) : res.x;
    float r1s = (ax1 < 0x38000000u) ? ((ax1 < 0x33800000u) ? x.y : t1) : res.y;
    res.x = r0;
    res.y = r1s;
  }
  return res;
}

// Both spike-interval deltas for counters {jc, jc+2^20}: bits -> uniform ->
// exponential -> / rate via packed Markstein CR division -> + 0.002.
// x = 1.0 - v is Sterbenz-exact == -(v - 1.0) == -uu (identical bits).
__device__ __forceinline__ f32x2 spike_delta_pair(uint32_t jc,
                                                  float rt, float ry) {
#pragma clang fp contract(off)
  uint32_t p0, p1, q0i, q1i;
  threefry2x32_0_42(0u, jc, p0, p1);
  threefry2x32_0_42(0u, jc + 0x100000u, q0i, q1i);
  uint32_t bits0 = p0 ^ p1;
  uint32_t bits1 = q0i ^ q1i;
  f32x2 v = { __uint_as_float((bits0 >> 9) | 0x3f800000u),
              __uint_as_float((bits1 >> 9) | 0x3f800000u) };
  f32x2 x = 1.0f - v;                       // == -uu, exact
  f32x2 expo = -fdlibm_log1pf_pk(x);        // exact negation
  f32x2 ry2 = {ry, ry};
  f32x2 nrt = {-rt, -rt};
  f32x2 q0 = expo * ry2;                    // pk mul
  f32x2 rr = pk_fma(nrt, q0, expo);         // exact residual (fma)
  f32x2 qq = pk_fma(rr, ry2, q0);           // == RN(expo/rt)
  return qq + 0.002f;                       // pk add
}

__global__ void __launch_bounds__(256) poisson_count_kernel(
    const float* __restrict__ rates, int* __restrict__ out) {
#pragma clang fp contract(off)
  __shared__ uint32_t pool_idx[4][kEPW];   // local element index (LPT order)
  __shared__ float2   pool_ry[4][kEPW];    // {rate, RN(1/rate)} per element
  int wslot = (int)threadIdx.x >> 6;
  int lane  = (int)threadIdx.x & 63;
  int wid   = blockIdx.x * 4 + wslot;
  uint32_t base = (uint32_t)wid * kEPW;
  uint64_t lmask_lt = (1ull << lane) - 1ull;

  // ---- one-time setup: LPT buckets + hoisted CR f32 reciprocals ----
  {
    float r[4];
    int   bb[4];
    uint32_t pos[4];
#pragma unroll
    for (int i = 0; i < 4; ++i) {
      r[i] = rates[base + (uint32_t)(i * 64) + (uint32_t)lane];
      int q = (int)(r[i] * 0.4f);
      q = q > 7 ? 7 : q;
      bb[i] = 7 - q;                       // bucket 0 = highest rates
    }
    uint32_t off = 0;
#pragma unroll
    for (int b = 0; b < 8; ++b) {
      uint64_t m0 = __ballot(bb[0] == b);
      uint64_t m1 = __ballot(bb[1] == b);
      uint64_t m2 = __ballot(bb[2] == b);
      uint64_t m3 = __ballot(bb[3] == b);
      uint32_t c0 = (uint32_t)__popcll(m0);
      uint32_t c1 = (uint32_t)__popcll(m1);
      uint32_t c2 = (uint32_t)__popcll(m2);
      uint32_t c3 = (uint32_t)__popcll(m3);
      if (bb[0] == b) pos[0] = off + (uint32_t)__popcll(m0 & lmask_lt);
      if (bb[1] == b) pos[1] = off + c0 + (uint32_t)__popcll(m1 & lmask_lt);
      if (bb[2] == b) pos[2] = off + c0 + c1 + (uint32_t)__popcll(m2 & lmask_lt);
      if (bb[3] == b) pos[3] = off + c0 + c1 + c2 + (uint32_t)__popcll(m3 & lmask_lt);
      off += c0 + c1 + c2 + c3;
    }
#pragma unroll
    for (int i = 0; i < 4; ++i) {
      pool_idx[wslot][pos[i]] = (uint32_t)(i * 64) + (uint32_t)lane;
      // CR f32 reciprocal via f64 (setup-only f64; none in the main loop)
      pool_ry[wslot][pos[i]] = make_float2(r[i], (float)(1.0 / (double)r[i]));
    }
  }
  __syncthreads();

  // ---- main loop: ballot lane-refill; FOUR evals per round (2 pk chains) --
  uint32_t next = 0;                       // wave-uniform: elements handed out
  uint32_t o = 0;
  uint32_t jc = 0;                         // threefry counter = (s<<20) + o
  float run = 0.0f;
  int s = 0;                               // evals consumed (multiple of 4)
  float rt = 1.0f, ry = 1.0f;              // rate, RN(1/rate)
  bool active = false;

  while (true) {
    uint64_t needmask = __ballot(!active);
    if (needmask != 0ull) {
      uint32_t avail = kEPW - next;
      if (avail != 0u) {
        if (!active) {
          uint32_t rank = (uint32_t)__popcll(needmask & lmask_lt);
          if (rank < avail) {
            uint32_t slot = next + rank;
            o = base + pool_idx[wslot][slot];
            float2 ryv = pool_ry[wslot][slot];
            rt = ryv.x; ry = ryv.y;
            run = 0.0f; s = 0; jc = o;     // s=0 -> jc = o
            active = true;
          }
        }
        uint32_t nneed = (uint32_t)__popcll(needmask);
        next += (nneed < avail) ? nneed : avail;
      } else if (needmask == ~0ull) {
        break;                             // pool empty, all lanes idle
      }
    }

    if (active) {
      // TWO independent packed pipelines (chain-ILP x2, each pk-dual);
      // sequential RN cumsum across all four evals.
      f32x2 dA = spike_delta_pair(jc,             rt, ry);  // evals s, s+1
      f32x2 dB = spike_delta_pair(jc + 0x200000u, rt, ry);  // evals s+2, s+3
      float run1 = run  + dA.x;
      float run2 = run1 + dA.y;
      float run3 = run2 + dB.x;
      float run4 = run3 + dB.y;
      s += 4;
      bool lt1 = (run1 < 1.0f);
      bool lt2 = (run2 < 1.0f);
      bool lt3 = (run3 < 1.0f);
      bool lt4 = (run4 < 1.0f);
      // monotone cumsum: lt1 >= lt2 >= lt3 >= lt4; single exit branch.
      if (!lt4 || s == kSpikes) {
        // crossed in this quad -> count = (s-4) + #below; cap -> 100.
        out[o] = lt4 ? kSpikes
                     : (s - 4 + (int)lt1 + (int)lt2 + (int)lt3);
        active = false;
      } else {
        run = run4;
        jc += 0x400000u;                   // += 4*2^20
      }
    }
  }
}

extern "C" void kernel_launch(void* const* d_in, const int* in_sizes, int n_in,
                              void* d_out, int out_size, void* d_ws, size_t ws_size,
                              hipStream_t stream) {
  const float* rates = (const float*)d_in[0];
  int* out = (int*)d_out;
  (void)in_sizes; (void)n_in; (void)out_size; (void)d_ws; (void)ws_size;
  poisson_count_kernel<<<kBlocks, 256, 0, stream>>>(rates, out);
}

// Round 11
// 99.204 us; speedup vs baseline: 1.0210x; 1.0196x over previous
//
#include <hip/hip_runtime.h>
#include <stdint.h>

// PoissonNeuronTransform — bit-exact vs the harness's NUMPY reference (ref=np).
// Validated (absmax 0.0, R11-R18): threefry2x32 partitionable bits, uniform
// bit-trick, fdlibm log1pf port (dead c-branch removed, proof R17), +0.002f,
// sequential f32 cumsum, early exit (monotone RN-fadd), wave-internal ballot
// lane-refill, LPT (descending-rate) handout.
// R19: hoisted per-element f64 reciprocal into setup (LDS).
// R21/22: kEPW=256 (1024 blocks) straggler amortization. 62.5->59.3us.
// R23: 2-eval unroll (per-lane ILP). 59.3->57.4us.
// R24: Markstein CR division by rate (f64 out of the loop). 57.4->58.7.
// R25: Markstein division inside log1pf (vcc-free). 58.7->53.4us.
// R26: 6 waves/SIMD — REVERTED (53.4->54.7). Scheduling axis exhausted.
// R27: rare-path tiny-select ballot guard. 54.7->52.5us.  <== BEST
// R28: packed-f32 dual-eval. 52.5->54.2, VALUBusy 81->70 — REVERTED.
// R29: 2x independent packed chains. 54.2->56.5, busy 68 — REVERTED.
//   Conclusion: v_pk_*_f32 saves ISSUE slots, not EXECUTION throughput
//   (pipe does the same lane-work), and adds latency+packing. The kernel
//   is bound by sustained VALU execution (~4 cyc/wave-inst in EVERY config:
//   4/6/8 waves, ILP-1/2, pk/scalar). Only real instruction cuts move wall
//   time; none remain that preserve bit-exactness (poly truncation is
//   unprovable, threefry counters diverge at round 1, ILP-4's granularity
//   waste exceeds its gross gain per R23's diminishing curve).
// R30 (THIS ROUND): revert to R27 verbatim — the verified optimum.
//   Floor arithmetic: ~134 inst/eval x ~12.4 slots/elem x 2^20 elems /
//   1024 SIMDs ~ 25k inst/SIMD x ~4 cyc/inst ~ 100k cyc ~ 42us busy +
//   tail ~ 52us. This is the VALU execution roofline for this bit-exact
//   instruction stream.

static constexpr int      kSpikes = 100;              // NUM_SPIKES
static constexpr int      kBlocks = 1024;             // x256 thr = 4096 waves
static constexpr uint32_t kEPW    = 256;              // elements per wave

__device__ __forceinline__ uint32_t rotl32(uint32_t v, uint32_t d) {
  return (v << d) | (v >> (32u - d));
}

// threefry2x32 with key (0, 42) — matches jax.random.key(42).
__device__ __forceinline__ void threefry2x32_0_42(uint32_t x0, uint32_t x1,
                                                  uint32_t& o0, uint32_t& o1) {
  const uint32_t ks0 = 0u;
  const uint32_t ks1 = 42u;
  const uint32_t ks2 = 0x1BD11BDAu ^ 0u ^ 42u;
  uint32_t a = x0 + ks0;
  uint32_t b = x1 + ks1;
#define TF_ROUND(r) { a += b; b = rotl32(b, (r)); b ^= a; }
  TF_ROUND(13u) TF_ROUND(15u) TF_ROUND(26u) TF_ROUND(6u)
  a += ks1; b += ks2 + 1u;
  TF_ROUND(17u) TF_ROUND(29u) TF_ROUND(16u) TF_ROUND(24u)
  a += ks2; b += ks0 + 2u;
  TF_ROUND(13u) TF_ROUND(15u) TF_ROUND(26u) TF_ROUND(6u)
  a += ks0; b += ks1 + 3u;
  TF_ROUND(17u) TF_ROUND(29u) TF_ROUND(16u) TF_ROUND(24u)
  a += ks1; b += ks2 + 4u;
  TF_ROUND(13u) TF_ROUND(15u) TF_ROUND(26u) TF_ROUND(6u)
  a += ks2; b += ks0 + 5u;
#undef TF_ROUND
  o0 = a; o1 = b;
}

// Branchless fdlibm s_log1pf for x = -m*2^-23, m in [0, 2^23) — bit-exact
// (R12 port; c-branch removed, proof R17; R25 vcc-free Markstein division;
// R27 tiny-path selects hoisted behind a wave-uniform rare branch).
__device__ __forceinline__ float fdlibm_log1pf_nb(float x) {
#pragma clang fp contract(off)
  const float ln2_hi = __uint_as_float(0x3f317180u);
  const float ln2_lo = __uint_as_float(0x3717f7d1u);
  const float Lp1 = __uint_as_float(0x3F2AAAABu);
  const float Lp2 = __uint_as_float(0x3ECCCCCDu);
  const float Lp3 = __uint_as_float(0x3E924925u);
  const float Lp4 = __uint_as_float(0x3E638E29u);
  const float Lp5 = __uint_as_float(0x3E3A3325u);
  const float Lp6 = __uint_as_float(0x3E1CD04Fu);
  const float Lp7 = __uint_as_float(0x3E178897u);

  uint32_t hx = __float_as_uint(x);
  uint32_t ax = hx & 0x7fffffffu;

  float u = 1.0f + x;
  uint32_t hu = __float_as_uint(u);
  int k = (int)(hu >> 23) - 127;
  uint32_t m = hu & 0x007fffffu;
  bool half = (m >= 0x3504f7u);
  int k2 = half ? (k + 1) : k;
  float u2 = __uint_as_float(m | (half ? 0x3f000000u : 0x3f800000u));
  float f2 = u2 - 1.0f;

  bool cond0 = ((int32_t)hx <= (int32_t)0xbe95f61fu);
  float kf = cond0 ? 0.0f : (float)k2;
  float ff = cond0 ? x : f2;

  float hfsq = (0.5f * ff) * ff;
  // Markstein division s = RN(ff / (2+ff)), vcc-free (R25):
  float den = 2.0f + ff;
  float y0 = __builtin_amdgcn_rcpf(den);   // v_rcp_f32, <=1 ulp
  float e  = fmaf(-den, y0, 1.0f);         // exact-fma residual
  float y1 = fmaf(y0, e, y0);              // reciprocal err ~2^-25
  float q0 = ff * y1;
  float r1 = fmaf(-den, q0, ff);           // exact residual
  float s  = fmaf(r1, y1, q0);             // == RN(ff/den), Markstein
  float z = s * s;
  float R = z * (Lp1 + z * (Lp2 + z * (Lp3 + z * (Lp4 +
            z * (Lp5 + z * (Lp6 + z * Lp7))))));
  float lowsum = s * (hfsq + R) + kf * ln2_lo;
  float res = kf * ln2_hi - ((hfsq - lowsum) - ff);

  // R27: tiny path (|x| < 2^-15 <=> 23-bit m < 256, P = 2^-15/eval) taken
  // behind a wave-uniform rare branch; selects identical to the original.
  if (__builtin_expect(__ballot(ax < 0x38000000u) != 0ull, 0)) {
    float tiny2 = x - (x * x) * 0.5f;
    res = (ax < 0x38000000u) ? ((ax < 0x33800000u) ? x : tiny2) : res;
  }
  return res;
}

// One spike-interval delta for counter jc: bits -> uniform -> exponential
// -> / rate via Markstein CR division (rt = rate, ry = RN(1/rt)) -> + 0.002.
__device__ __forceinline__ float spike_delta(uint32_t jc, float rt, float ry) {
#pragma clang fp contract(off)
  uint32_t b1, b2;
  threefry2x32_0_42(0u, jc, b1, b2);
  uint32_t bits = b1 ^ b2;
  float uu = __uint_as_float((bits >> 9) | 0x3f800000u) - 1.0f;  // [0, 1)
  float expo = -fdlibm_log1pf_nb(-uu);
  float q0 = expo * ry;
  float rr = fmaf(-rt, q0, expo);          // exact residual (fma)
  float q  = fmaf(rr, ry, q0);             // == RN(expo/rt)
  return q + 0.002f;
}

__global__ void __launch_bounds__(256) poisson_count_kernel(
    const float* __restrict__ rates, int* __restrict__ out) {
#pragma clang fp contract(off)
  __shared__ uint32_t pool_idx[4][kEPW];   // local element index (LPT order)
  __shared__ float2   pool_ry[4][kEPW];    // {rate, RN(1/rate)} per element
  int wslot = (int)threadIdx.x >> 6;
  int lane  = (int)threadIdx.x & 63;
  int wid   = blockIdx.x * 4 + wslot;
  uint32_t base = (uint32_t)wid * kEPW;
  uint64_t lmask_lt = (1ull << lane) - 1ull;

  // ---- one-time setup: LPT buckets + hoisted CR f32 reciprocals ----
  {
    float r[4];
    int   bb[4];
    uint32_t pos[4];
#pragma unroll
    for (int i = 0; i < 4; ++i) {
      r[i] = rates[base + (uint32_t)(i * 64) + (uint32_t)lane];
      int q = (int)(r[i] * 0.4f);
      q = q > 7 ? 7 : q;
      bb[i] = 7 - q;                       // bucket 0 = highest rates
    }
    uint32_t off = 0;
#pragma unroll
    for (int b = 0; b < 8; ++b) {
      uint64_t m0 = __ballot(bb[0] == b);
      uint64_t m1 = __ballot(bb[1] == b);
      uint64_t m2 = __ballot(bb[2] == b);
      uint64_t m3 = __ballot(bb[3] == b);
      uint32_t c0 = (uint32_t)__popcll(m0);
      uint32_t c1 = (uint32_t)__popcll(m1);
      uint32_t c2 = (uint32_t)__popcll(m2);
      uint32_t c3 = (uint32_t)__popcll(m3);
      if (bb[0] == b) pos[0] = off + (uint32_t)__popcll(m0 & lmask_lt);
      if (bb[1] == b) pos[1] = off + c0 + (uint32_t)__popcll(m1 & lmask_lt);
      if (bb[2] == b) pos[2] = off + c0 + c1 + (uint32_t)__popcll(m2 & lmask_lt);
      if (bb[3] == b) pos[3] = off + c0 + c1 + c2 + (uint32_t)__popcll(m3 & lmask_lt);
      off += c0 + c1 + c2 + c3;
    }
#pragma unroll
    for (int i = 0; i < 4; ++i) {
      pool_idx[wslot][pos[i]] = (uint32_t)(i * 64) + (uint32_t)lane;
      // CR f32 reciprocal via f64 (setup-only f64; none in the main loop)
      pool_ry[wslot][pos[i]] = make_float2(r[i], (float)(1.0 / (double)r[i]));
    }
  }
  __syncthreads();

  // ---- main loop: ballot lane-refill; TWO sequential evals per round ----
  uint32_t next = 0;                       // wave-uniform: elements handed out
  uint32_t o = 0;
  uint32_t jc = 0;                         // threefry counter = (s<<20) + o
  float run = 0.0f;
  int s = 0;                               // evals consumed (always even)
  float rt = 1.0f, ry = 1.0f;              // rate, RN(1/rate)
  bool active = false;

  while (true) {
    uint64_t needmask = __ballot(!active);
    if (needmask != 0ull) {
      uint32_t avail = kEPW - next;
      if (avail != 0u) {
        if (!active) {
          uint32_t rank = (uint32_t)__popcll(needmask & lmask_lt);
          if (rank < avail) {
            uint32_t slot = next + rank;
            o = base + pool_idx[wslot][slot];
            float2 ryv = pool_ry[wslot][slot];
            rt = ryv.x; ry = ryv.y;
            run = 0.0f; s = 0; jc = o;     // s=0 -> jc = o
            active = true;
          }
        }
        uint32_t nneed = (uint32_t)__popcll(needmask);
        next += (nneed < avail) ? nneed : avail;
      } else if (needmask == ~0ull) {
        break;                             // pool empty, all lanes idle
      }
    }

    if (active) {
      // Two independent delta pipelines (ILP x2); sequential RN cumsum.
      float d1 = spike_delta(jc, rt, ry);             // eval s
      float d2 = spike_delta(jc + 0x100000u, rt, ry); // eval s+1 (2^20)
      float run1 = run + d1;
      float run2 = run1 + d2;
      s += 2;
      bool lt1 = (run1 < 1.0f);
      bool lt2 = (run2 < 1.0f);
      // monotone: d2 > 0 => (lt2 => lt1); single exit branch.
      if (!lt2 || s == kSpikes) {
        // count: crossed in this pair -> lt1 ? s-1 : s-2; else cap -> 100.
        out[o] = lt2 ? kSpikes : (lt1 ? (s - 1) : (s - 2));
        active = false;
      } else {
        run = run2;
        jc += 0x200000u;                   // += 2*2^20
      }
    }
  }
}

extern "C" void kernel_launch(void* const* d_in, const int* in_sizes, int n_in,
                              void* d_out, int out_size, void* d_ws, size_t ws_size,
                              hipStream_t stream) {
  const float* rates = (const float*)d_in[0];
  int* out = (int*)d_out;
  (void)in_sizes; (void)n_in; (void)out_size; (void)d_ws; (void)ws_size;
  poisson_count_kernel<<<kBlocks, 256, 0, stream>>>(rates, out);
}